// Round 1
// baseline (4463.224 us; speedup 1.0000x reference)
//
#include <hip/hip_runtime.h>

typedef _Float16 half_t;
typedef _Float16 h2_t __attribute__((ext_vector_type(2)));
typedef _Float16 h8_t __attribute__((ext_vector_type(8)));
typedef float f32x4 __attribute__((ext_vector_type(4)));

#define BQ 64
#define TT 2048
#define EE 256
#define HH 256
#define NG 768  // 3*H gate rows, order [u, r, n]

#if defined(__has_builtin)
#if __has_builtin(__builtin_amdgcn_fdot2)
#define HAVE_FDOT2 1
#endif
#endif

__device__ __forceinline__ float fdot2_acc(h2_t a, h2_t b, float c) {
#ifdef HAVE_FDOT2
  return __builtin_amdgcn_fdot2(a, b, c, false);
#else
  return c + (float)a[0] * (float)b[0] + (float)a[1] * (float)b[1];
#endif
}

// ---------------- Phase A: gates[t][b][n] = x[b][t][:] . W{g}_x[j][:] + bias ----------------
// grid: (Tc, 16). Tile: M=64 (all batches at one t), N=48, K=256 (full).
__global__ __launch_bounds__(256) void gru_xproj(
    const float* __restrict__ x,
    const float* __restrict__ Wu, const float* __restrict__ bu,
    const float* __restrict__ Wr, const float* __restrict__ br,
    const float* __restrict__ Wn, const float* __restrict__ bn,
    half_t* __restrict__ gates, int t0)
{
  __shared__ half_t Asm[64][256];  // 32 KB
  __shared__ half_t Bsm[48][256];  // 24 KB
  const int tid = threadIdx.x;
  const int tl = blockIdx.x;
  const int n0 = blockIdx.y * 48;
  const int t = t0 + tl;

  {  // A tile: rows = batch, cols = E. 4 threads per row.
    const int row = tid >> 2, part = tid & 3;
    const float4* xp = (const float4*)(x + ((size_t)row * TT + t) * EE + part * 64);
#pragma unroll
    for (int i = 0; i < 16; ++i) {
      float4 v = xp[i];
      int c = part * 64 + i * 4;
      Asm[row][c + 0] = (half_t)v.x; Asm[row][c + 1] = (half_t)v.y;
      Asm[row][c + 2] = (half_t)v.z; Asm[row][c + 3] = (half_t)v.w;
    }
  }
  if (tid < 192) {  // B tile: rows = gate-row n, cols = E (x-part of W)
    const int row = tid >> 2, part = tid & 3;
    const int n = n0 + row;
    const int gsel = n >> 8, jj = n & 255;
    const float* W = (gsel == 0) ? Wu : (gsel == 1) ? Wr : Wn;
    const float4* wp = (const float4*)(W + (size_t)jj * (EE + HH) + part * 64);
#pragma unroll
    for (int i = 0; i < 16; ++i) {
      float4 v = wp[i];
      int c = part * 64 + i * 4;
      Bsm[row][c + 0] = (half_t)v.x; Bsm[row][c + 1] = (half_t)v.y;
      Bsm[row][c + 2] = (half_t)v.z; Bsm[row][c + 3] = (half_t)v.w;
    }
  }
  __syncthreads();

  const int wv = tid >> 6, lane = tid & 63;
  const int rowa = wv * 16 + (lane & 15);
  const int koff = (lane >> 4) * 8;
  f32x4 acc0 = {0.f, 0.f, 0.f, 0.f}, acc1 = acc0, acc2 = acc0;
#pragma unroll
  for (int ki = 0; ki < 8; ++ki) {
    h8_t af = *(const h8_t*)&Asm[rowa][ki * 32 + koff];
    h8_t b0 = *(const h8_t*)&Bsm[0  + (lane & 15)][ki * 32 + koff];
    h8_t b1 = *(const h8_t*)&Bsm[16 + (lane & 15)][ki * 32 + koff];
    h8_t b2 = *(const h8_t*)&Bsm[32 + (lane & 15)][ki * 32 + koff];
    acc0 = __builtin_amdgcn_mfma_f32_16x16x32_f16(af, b0, acc0, 0, 0, 0);
    acc1 = __builtin_amdgcn_mfma_f32_16x16x32_f16(af, b1, acc1, 0, 0, 0);
    acc2 = __builtin_amdgcn_mfma_f32_16x16x32_f16(af, b2, acc2, 0, 0, 0);
  }
  // D layout: col = lane&15, row(in 16-tile) = (lane>>4)*4 + reg
  const int colc = lane & 15;
  const int rbase = wv * 16 + (lane >> 4) * 4;
#pragma unroll
  for (int nt = 0; nt < 3; ++nt) {
    f32x4 a = (nt == 0) ? acc0 : (nt == 1) ? acc1 : acc2;
    int n = n0 + nt * 16 + colc;
    int gsel = n >> 8, jj = n & 255;
    const float* bp = (gsel == 0) ? bu : (gsel == 1) ? br : bn;
    float bias = bp[jj];
#pragma unroll
    for (int rr = 0; rr < 4; ++rr) {
      int m = rbase + rr;  // = batch index
      gates[((size_t)tl * 64 + m) * NG + n] = (half_t)(a[rr] + bias);
    }
  }
}

// ---------------- Phase B: sequential scan, one workgroup per batch ----------------
// 768 threads: thread r owns gate-row (g = r>>8 in {u,r,n}, j = r&255); its
// recurrent weight row lives in 128 packed-f16 VGPRs. rt uses Wu/xu, zt uses
// Wr/xr (reference naming quirk); n-gate input is (rt*h) @ Wn_h^T.
__global__ __launch_bounds__(768, 3) void gru_rec(
    const half_t* __restrict__ gates,
    const float* __restrict__ h0,
    const float* __restrict__ Wu, const float* __restrict__ Wr,
    const float* __restrict__ Wn,
    float* __restrict__ hs, float* __restrict__ ht,
    float* __restrict__ hws, int t0, int t1)
{
  __shared__ __align__(16) half_t h2buf[256];
  __shared__ __align__(16) half_t rh2buf[256];
  __shared__ float zbuf[256];
  __shared__ float hmbuf[256];

  const int b = blockIdx.x;
  const int r = threadIdx.x;
  const int g = r >> 8;
  const int j = r & 255;

  h2_t w[128];
  {
    const float* W = (g == 0) ? Wu : (g == 1) ? Wr : Wn;
    const float4* wp = (const float4*)(W + (size_t)j * (EE + HH) + EE);
#pragma unroll
    for (int i = 0; i < 64; ++i) {
      float4 v = wp[i];
      h2_t p0; p0[0] = (half_t)v.x; p0[1] = (half_t)v.y;
      h2_t p1; p1[0] = (half_t)v.z; p1[1] = (half_t)v.w;
      w[2 * i + 0] = p0;
      w[2 * i + 1] = p1;
    }
  }

  if (r < 256) {
    float hv = (t0 == 0) ? h0[b * HH + j] : hws[b * HH + j];
    hmbuf[j] = hv;
    h2buf[j] = (half_t)hv;
  }
  __syncthreads();

  const half_t* gb = gates + (size_t)b * NG + r;  // step stride = 64*NG
  const int nT = t1 - t0;
  float xc = (float)gb[0];

  for (int tl = 0; tl < nT; ++tl) {
    float xnext = 0.f;
    if (tl + 1 < nT) xnext = (float)gb[(size_t)(tl + 1) * 64 * NG];  // prefetch

    // phase 1: u,r gate matvecs over h
    if (r < 512) {
      float a0 = 0.f, a1 = 0.f, a2 = 0.f, a3 = 0.f;
#pragma unroll
      for (int kk = 0; kk < 32; ++kk) {
        h8_t hv = *(const h8_t*)(h2buf + 8 * kk);
        a0 = fdot2_acc(w[4 * kk + 0], __builtin_shufflevector(hv, hv, 0, 1), a0);
        a1 = fdot2_acc(w[4 * kk + 1], __builtin_shufflevector(hv, hv, 2, 3), a1);
        a2 = fdot2_acc(w[4 * kk + 2], __builtin_shufflevector(hv, hv, 4, 5), a2);
        a3 = fdot2_acc(w[4 * kk + 3], __builtin_shufflevector(hv, hv, 6, 7), a3);
      }
      float pre = xc + ((a0 + a1) + (a2 + a3));
      pre = fminf(fmaxf(pre, -30.f), 30.f);
      float sg = 1.f / (1.f + __expf(-pre));
      if (r < 256) {
        rh2buf[j] = (half_t)(sg * hmbuf[j]);  // rt * h  (pre-matmul!)
      } else {
        zbuf[j] = sg;                          // zt
      }
    }
    __syncthreads();

    // phase 2: n gate matvec over rt*h, then state update
    if (r >= 512) {
      float c0 = 0.f, c1 = 0.f, c2 = 0.f, c3 = 0.f;
#pragma unroll
      for (int kk = 0; kk < 32; ++kk) {
        h8_t hv = *(const h8_t*)(rh2buf + 8 * kk);
        c0 = fdot2_acc(w[4 * kk + 0], __builtin_shufflevector(hv, hv, 0, 1), c0);
        c1 = fdot2_acc(w[4 * kk + 1], __builtin_shufflevector(hv, hv, 2, 3), c1);
        c2 = fdot2_acc(w[4 * kk + 2], __builtin_shufflevector(hv, hv, 4, 5), c2);
        c3 = fdot2_acc(w[4 * kk + 3], __builtin_shufflevector(hv, hv, 6, 7), c3);
      }
      float pre = xc + ((c0 + c1) + (c2 + c3));
      pre = fminf(fmaxf(pre, -15.f), 15.f);
      float e = __expf(-2.f * pre);
      float ntv = (1.f - e) / (1.f + e);  // tanh
      float z = zbuf[j];
      float hn = (1.f - z) * ntv + z * hmbuf[j];
      hmbuf[j] = hn;
      h2buf[j] = (half_t)hn;
      hs[((size_t)b * TT + (t0 + tl)) * HH + j] = hn;
    }
    __syncthreads();
    xc = xnext;
  }

  if (r < 256) {
    float hv = hmbuf[j];
    if (t1 == TT) ht[b * HH + j] = hv;
    else hws[b * HH + j] = hv;
  }
}

extern "C" void kernel_launch(void* const* d_in, const int* in_sizes, int n_in,
                              void* d_out, int out_size, void* d_ws, size_t ws_size,
                              hipStream_t stream)
{
  (void)in_sizes; (void)n_in; (void)out_size;
  const float* x  = (const float*)d_in[0];
  const float* h0 = (const float*)d_in[1];
  const float* Wu = (const float*)d_in[2];
  const float* bu = (const float*)d_in[3];
  const float* Wr = (const float*)d_in[4];
  const float* br = (const float*)d_in[5];
  const float* Wn = (const float*)d_in[6];
  const float* bn = (const float*)d_in[7];
  float* hs = (float*)d_out;
  float* ht = hs + (size_t)BQ * TT * HH;
  float* hws = (float*)d_ws;
  half_t* gates = (half_t*)((char*)d_ws + 65536);

  const size_t per_step = (size_t)BQ * NG * sizeof(half_t);  // 98304 B
  size_t avail = (ws_size > 65536) ? ws_size - 65536 : 0;
  int Tc = (int)(avail / per_step);
  if (Tc > TT) Tc = TT;
  if (Tc < 1) Tc = 1;

  for (int t0 = 0; t0 < TT; t0 += Tc) {
    int tc = (TT - t0 < Tc) ? (TT - t0) : Tc;
    gru_xproj<<<dim3(tc, 16), 256, 0, stream>>>(x, Wu, bu, Wr, br, Wn, bn, gates, t0);
    gru_rec<<<dim3(BQ), 768, 0, stream>>>(gates, h0, Wu, Wr, Wn, hs, ht, hws, t0, t0 + tc);
  }
}

// Round 2
// 3639.183 us; speedup vs baseline: 1.2264x; 1.2264x over previous
//
#include <hip/hip_runtime.h>

typedef _Float16 half_t;
typedef _Float16 h2_t __attribute__((ext_vector_type(2)));
typedef _Float16 h8_t __attribute__((ext_vector_type(8)));
typedef float f32x4 __attribute__((ext_vector_type(4)));

#define BQ 64
#define TT 2048
#define EE 256
#define HH 256
#define NG 768  // 3*H gate rows, order [u, r, n]

#if defined(__has_builtin)
#if __has_builtin(__builtin_amdgcn_fdot2)
#define HAVE_FDOT2 1
#endif
#endif

__device__ __forceinline__ float fdot2_acc(h2_t a, h2_t b, float c) {
#ifdef HAVE_FDOT2
  return __builtin_amdgcn_fdot2(a, b, c, false);
#else
  return c + (float)a[0] * (float)b[0] + (float)a[1] * (float)b[1];
#endif
}

// ---------------- Phase A: gates[t][b][n] = x[b][t][:] . W{g}_x[j][:] + bias ----------------
// grid: (Tc, 16). Tile: M=64 (all batches at one t), N=48, K=256 (full).
__global__ __launch_bounds__(256) void gru_xproj(
    const float* __restrict__ x,
    const float* __restrict__ Wu, const float* __restrict__ bu,
    const float* __restrict__ Wr, const float* __restrict__ br,
    const float* __restrict__ Wn, const float* __restrict__ bn,
    half_t* __restrict__ gates, int t0)
{
  __shared__ half_t Asm[64][256];  // 32 KB
  __shared__ half_t Bsm[48][256];  // 24 KB
  const int tid = threadIdx.x;
  const int tl = blockIdx.x;
  const int n0 = blockIdx.y * 48;
  const int t = t0 + tl;

  {  // A tile: rows = batch, cols = E. 4 threads per row.
    const int row = tid >> 2, part = tid & 3;
    const float4* xp = (const float4*)(x + ((size_t)row * TT + t) * EE + part * 64);
#pragma unroll
    for (int i = 0; i < 16; ++i) {
      float4 v = xp[i];
      int c = part * 64 + i * 4;
      Asm[row][c + 0] = (half_t)v.x; Asm[row][c + 1] = (half_t)v.y;
      Asm[row][c + 2] = (half_t)v.z; Asm[row][c + 3] = (half_t)v.w;
    }
  }
  if (tid < 192) {  // B tile: rows = gate-row n, cols = E (x-part of W)
    const int row = tid >> 2, part = tid & 3;
    const int n = n0 + row;
    const int gsel = n >> 8, jj = n & 255;
    const float* W = (gsel == 0) ? Wu : (gsel == 1) ? Wr : Wn;
    const float4* wp = (const float4*)(W + (size_t)jj * (EE + HH) + part * 64);
#pragma unroll
    for (int i = 0; i < 16; ++i) {
      float4 v = wp[i];
      int c = part * 64 + i * 4;
      Bsm[row][c + 0] = (half_t)v.x; Bsm[row][c + 1] = (half_t)v.y;
      Bsm[row][c + 2] = (half_t)v.z; Bsm[row][c + 3] = (half_t)v.w;
    }
  }
  __syncthreads();

  const int wv = tid >> 6, lane = tid & 63;
  const int rowa = wv * 16 + (lane & 15);
  const int koff = (lane >> 4) * 8;
  f32x4 acc0 = {0.f, 0.f, 0.f, 0.f}, acc1 = acc0, acc2 = acc0;
#pragma unroll
  for (int ki = 0; ki < 8; ++ki) {
    h8_t af = *(const h8_t*)&Asm[rowa][ki * 32 + koff];
    h8_t b0 = *(const h8_t*)&Bsm[0  + (lane & 15)][ki * 32 + koff];
    h8_t b1 = *(const h8_t*)&Bsm[16 + (lane & 15)][ki * 32 + koff];
    h8_t b2 = *(const h8_t*)&Bsm[32 + (lane & 15)][ki * 32 + koff];
    acc0 = __builtin_amdgcn_mfma_f32_16x16x32_f16(af, b0, acc0, 0, 0, 0);
    acc1 = __builtin_amdgcn_mfma_f32_16x16x32_f16(af, b1, acc1, 0, 0, 0);
    acc2 = __builtin_amdgcn_mfma_f32_16x16x32_f16(af, b2, acc2, 0, 0, 0);
  }
  // D layout: col = lane&15, row(in 16-tile) = (lane>>4)*4 + reg
  const int colc = lane & 15;
  const int rbase = wv * 16 + (lane >> 4) * 4;
#pragma unroll
  for (int nt = 0; nt < 3; ++nt) {
    f32x4 a = (nt == 0) ? acc0 : (nt == 1) ? acc1 : acc2;
    int n = n0 + nt * 16 + colc;
    int gsel = n >> 8, jj = n & 255;
    const float* bp = (gsel == 0) ? bu : (gsel == 1) ? br : bn;
    float bias = bp[jj];
#pragma unroll
    for (int rr = 0; rr < 4; ++rr) {
      int m = rbase + rr;  // = batch index
      gates[((size_t)tl * 64 + m) * NG + n] = (half_t)(a[rr] + bias);
    }
  }
}

// ---------------- Phase B: sequential scan, one workgroup per batch ----------------
// 512 threads (8 waves = 2/SIMD -> 256 VGPR cap, weights stay in VGPRs).
// Phase 1: thread r owns full u/r gate row r (w1[128] packed f16).
// Phase 2: pair (2m,2m+1) owns n-gate row m, K-halves (w2[64]); combine via shfl_xor(1).
// rt uses Wu/xu, zt uses Wr/xr (reference naming quirk); n-gate input is (rt*h) @ Wn_h^T.
__global__ __launch_bounds__(512, 2) void gru_rec(
    const half_t* __restrict__ gates,
    const float* __restrict__ h0,
    const float* __restrict__ Wu, const float* __restrict__ Wr,
    const float* __restrict__ Wn,
    float* __restrict__ hs, float* __restrict__ ht,
    float* __restrict__ hws, int t0, int t1)
{
  __shared__ __align__(16) half_t h2buf[256];
  __shared__ __align__(16) half_t rh2buf[256];
  __shared__ float zbuf[256];
  __shared__ float hmbuf[256];

  const int b = blockIdx.x;
  const int r = threadIdx.x;
  const int j1 = r & 255;          // phase-1 row within its gate
  const int m = r >> 1;            // phase-2 n-row
  const int p = r & 1;             // phase-2 K-half

  // phase-1 weights: u rows for r<256, r rows for r>=256
  h2_t w1[128];
  {
    const float* W = (r < 256) ? Wu : Wr;
    const float4* wp = (const float4*)(W + (size_t)j1 * (EE + HH) + EE);
#pragma unroll
    for (int i = 0; i < 64; ++i) {
      float4 v = wp[i];
      h2_t p0; p0[0] = (half_t)v.x; p0[1] = (half_t)v.y;
      h2_t p1; p1[0] = (half_t)v.z; p1[1] = (half_t)v.w;
      w1[2 * i + 0] = p0;
      w1[2 * i + 1] = p1;
    }
  }
  // phase-2 weights: n-row m, h-cols [128p, 128p+128)
  h2_t w2[64];
  {
    const float4* wp = (const float4*)(Wn + (size_t)m * (EE + HH) + EE + 128 * p);
#pragma unroll
    for (int i = 0; i < 32; ++i) {
      float4 v = wp[i];
      h2_t p0; p0[0] = (half_t)v.x; p0[1] = (half_t)v.y;
      h2_t p1; p1[0] = (half_t)v.z; p1[1] = (half_t)v.w;
      w2[2 * i + 0] = p0;
      w2[2 * i + 1] = p1;
    }
  }

  if (r < 256) {
    float hv = (t0 == 0) ? h0[b * HH + j1] : hws[b * HH + j1];
    hmbuf[j1] = hv;
    h2buf[j1] = (half_t)hv;
  }
  __syncthreads();

  const size_t gstride = (size_t)64 * NG;                 // per-step stride
  const half_t* g1 = gates + (size_t)b * NG + r;          // u/r gate value
  const half_t* g2 = gates + (size_t)b * NG + 512 + m;    // n gate value
  const int nT = t1 - t0;
  float x1 = (float)g1[0];
  float x2 = (float)g2[0];

  for (int tl = 0; tl < nT; ++tl) {
    const int tn = (tl + 1 < nT) ? (tl + 1) : (nT - 1);
    float x1n = (float)g1[(size_t)tn * gstride];  // prefetch next step
    float x2n = (float)g2[(size_t)tn * gstride];

    // phase 1: u,r gate matvecs over h (all 512 threads)
    {
      float a0 = 0.f, a1 = 0.f, a2 = 0.f, a3 = 0.f;
#pragma unroll
      for (int kk = 0; kk < 32; ++kk) {
        h8_t hv = *(const h8_t*)(h2buf + 8 * kk);
        a0 = fdot2_acc(w1[4 * kk + 0], __builtin_shufflevector(hv, hv, 0, 1), a0);
        a1 = fdot2_acc(w1[4 * kk + 1], __builtin_shufflevector(hv, hv, 2, 3), a1);
        a2 = fdot2_acc(w1[4 * kk + 2], __builtin_shufflevector(hv, hv, 4, 5), a2);
        a3 = fdot2_acc(w1[4 * kk + 3], __builtin_shufflevector(hv, hv, 6, 7), a3);
      }
      float pre = x1 + ((a0 + a1) + (a2 + a3));
      pre = fminf(fmaxf(pre, -30.f), 30.f);
      float sg = 1.f / (1.f + __expf(-pre));
      if (r < 256) {
        rh2buf[j1] = (half_t)(sg * hmbuf[j1]);  // rt * h  (pre-matmul!)
      } else {
        zbuf[j1] = sg;                           // zt
      }
    }
    __syncthreads();

    // phase 2: n gate matvec over rt*h (K-half per thread), then state update
    {
      float c0 = 0.f, c1 = 0.f, c2 = 0.f, c3 = 0.f;
      const half_t* rp = rh2buf + 128 * p;
#pragma unroll
      for (int kk = 0; kk < 16; ++kk) {
        h8_t hv = *(const h8_t*)(rp + 8 * kk);
        c0 = fdot2_acc(w2[4 * kk + 0], __builtin_shufflevector(hv, hv, 0, 1), c0);
        c1 = fdot2_acc(w2[4 * kk + 1], __builtin_shufflevector(hv, hv, 2, 3), c1);
        c2 = fdot2_acc(w2[4 * kk + 2], __builtin_shufflevector(hv, hv, 4, 5), c2);
        c3 = fdot2_acc(w2[4 * kk + 3], __builtin_shufflevector(hv, hv, 6, 7), c3);
      }
      float part = (c0 + c1) + (c2 + c3);
      float nsum = part + __shfl_xor(part, 1, 64);
      if (p == 0) {
        float pre = x2 + nsum;
        pre = fminf(fmaxf(pre, -15.f), 15.f);
        float e = __expf(-2.f * pre);
        float ntv = (1.f - e) / (1.f + e);  // tanh
        float z = zbuf[m];
        float hm = hmbuf[m];
        float hn = (1.f - z) * ntv + z * hm;
        hmbuf[m] = hn;
        h2buf[m] = (half_t)hn;
        hs[((size_t)b * TT + (t0 + tl)) * HH + m] = hn;
      }
    }
    __syncthreads();
    x1 = x1n;
    x2 = x2n;
  }

  if (r < 256) {
    float hv = hmbuf[j1];
    if (t1 == TT) ht[b * HH + j1] = hv;
    else hws[b * HH + j1] = hv;
  }
}

extern "C" void kernel_launch(void* const* d_in, const int* in_sizes, int n_in,
                              void* d_out, int out_size, void* d_ws, size_t ws_size,
                              hipStream_t stream)
{
  (void)in_sizes; (void)n_in; (void)out_size;
  const float* x  = (const float*)d_in[0];
  const float* h0 = (const float*)d_in[1];
  const float* Wu = (const float*)d_in[2];
  const float* bu = (const float*)d_in[3];
  const float* Wr = (const float*)d_in[4];
  const float* br = (const float*)d_in[5];
  const float* Wn = (const float*)d_in[6];
  const float* bn = (const float*)d_in[7];
  float* hs = (float*)d_out;
  float* ht = hs + (size_t)BQ * TT * HH;
  float* hws = (float*)d_ws;
  half_t* gates = (half_t*)((char*)d_ws + 65536);

  const size_t per_step = (size_t)BQ * NG * sizeof(half_t);  // 98304 B
  size_t avail = (ws_size > 65536) ? ws_size - 65536 : 0;
  int Tc = (int)(avail / per_step);
  if (Tc > TT) Tc = TT;
  if (Tc < 1) Tc = 1;

  for (int t0 = 0; t0 < TT; t0 += Tc) {
    int tc = (TT - t0 < Tc) ? (TT - t0) : Tc;
    gru_xproj<<<dim3(tc, 16), 256, 0, stream>>>(x, Wu, bu, Wr, br, Wn, bn, gates, t0);
    gru_rec<<<dim3(BQ), 512, 0, stream>>>(gates, h0, Wu, Wr, Wn, hs, ht, hws, t0, t0 + tc);
  }
}

// Round 3
// 3230.751 us; speedup vs baseline: 1.3815x; 1.1264x over previous
//
#include <hip/hip_runtime.h>

typedef _Float16 half_t;
typedef _Float16 h2_t __attribute__((ext_vector_type(2)));
typedef _Float16 h8_t __attribute__((ext_vector_type(8)));
typedef float f32x4 __attribute__((ext_vector_type(4)));
typedef unsigned int uint32;

#define BQ 64
#define TT 2048
#define EE 256
#define HH 256
#define NG 768  // 3*H gate rows, order [u, r, n]

#if defined(__has_builtin)
#if __has_builtin(__builtin_amdgcn_fdot2)
#define HAVE_FDOT2 1
#endif
#if __has_builtin(__builtin_amdgcn_rcpf)
#define FRCP(x) __builtin_amdgcn_rcpf(x)
#endif
#endif
#ifndef FRCP
#define FRCP(x) (1.0f / (x))
#endif

__device__ __forceinline__ float fdot2_acc(h2_t a, h2_t b, float c) {
#ifdef HAVE_FDOT2
  return __builtin_amdgcn_fdot2(a, b, c, false);
#else
  return c + (float)a[0] * (float)b[0] + (float)a[1] * (float)b[1];
#endif
}

// interleaved h layout: element k lives at half-index 16*((k&127)>>3) + 8*(k>>7) + (k&7)
// so K-half p's chunk c is h8-chunk (2c+p): even/odd lanes hit disjoint banks.
__device__ __forceinline__ int hidx(int k) {
  return 16 * ((k & 127) >> 3) + 8 * (k >> 7) + (k & 7);
}

// barrier that does NOT drain vmcnt: global prefetch stays in flight
__device__ __forceinline__ void barrier_lgkm() {
  asm volatile("s_waitcnt lgkmcnt(0)\n\ts_barrier" ::: "memory");
}

__device__ __forceinline__ float sigmoid_f(float x) {
  x = fminf(fmaxf(x, -30.f), 30.f);
  return FRCP(1.f + __expf(-x));
}

// ---------------- Phase A: input projections ----------------
// u/r gates (f16 pair) packed into the hs output slot [b][t][j] (overwritten by
// rec with h later); n gates into nbuf chunk. grid: (Tc, 16), tile M=64,N=48,K=256.
__global__ __launch_bounds__(256) void gru_xproj(
    const float* __restrict__ x,
    const float* __restrict__ Wu, const float* __restrict__ bu,
    const float* __restrict__ Wr, const float* __restrict__ br,
    const float* __restrict__ Wn, const float* __restrict__ bn,
    float* __restrict__ hs, half_t* __restrict__ nbuf, int t0)
{
  __shared__ half_t Asm[64][256];  // 32 KB
  __shared__ half_t Bsm[48][256];  // 24 KB
  const int tid = threadIdx.x;
  const int tl = blockIdx.x;
  const int n0 = blockIdx.y * 48;
  const int t = t0 + tl;

  {  // A tile: rows = batch, cols = E
    const int row = tid >> 2, part = tid & 3;
    const float4* xp = (const float4*)(x + ((size_t)row * TT + t) * EE + part * 64);
#pragma unroll
    for (int i = 0; i < 16; ++i) {
      float4 v = xp[i];
      int c = part * 64 + i * 4;
      Asm[row][c + 0] = (half_t)v.x; Asm[row][c + 1] = (half_t)v.y;
      Asm[row][c + 2] = (half_t)v.z; Asm[row][c + 3] = (half_t)v.w;
    }
  }
  if (tid < 192) {  // B tile: rows = gate-row n, cols = E (x-part of W)
    const int row = tid >> 2, part = tid & 3;
    const int n = n0 + row;
    const int gsel = n >> 8, jj = n & 255;
    const float* W = (gsel == 0) ? Wu : (gsel == 1) ? Wr : Wn;
    const float4* wp = (const float4*)(W + (size_t)jj * (EE + HH) + part * 64);
#pragma unroll
    for (int i = 0; i < 16; ++i) {
      float4 v = wp[i];
      int c = part * 64 + i * 4;
      Bsm[row][c + 0] = (half_t)v.x; Bsm[row][c + 1] = (half_t)v.y;
      Bsm[row][c + 2] = (half_t)v.z; Bsm[row][c + 3] = (half_t)v.w;
    }
  }
  __syncthreads();

  const int wv = tid >> 6, lane = tid & 63;
  const int rowa = wv * 16 + (lane & 15);
  const int koff = (lane >> 4) * 8;
  f32x4 acc0 = {0.f, 0.f, 0.f, 0.f}, acc1 = acc0, acc2 = acc0;
#pragma unroll
  for (int ki = 0; ki < 8; ++ki) {
    h8_t af = *(const h8_t*)&Asm[rowa][ki * 32 + koff];
    h8_t b0 = *(const h8_t*)&Bsm[0  + (lane & 15)][ki * 32 + koff];
    h8_t b1 = *(const h8_t*)&Bsm[16 + (lane & 15)][ki * 32 + koff];
    h8_t b2 = *(const h8_t*)&Bsm[32 + (lane & 15)][ki * 32 + koff];
    acc0 = __builtin_amdgcn_mfma_f32_16x16x32_f16(af, b0, acc0, 0, 0, 0);
    acc1 = __builtin_amdgcn_mfma_f32_16x16x32_f16(af, b1, acc1, 0, 0, 0);
    acc2 = __builtin_amdgcn_mfma_f32_16x16x32_f16(af, b2, acc2, 0, 0, 0);
  }
  const int colc = lane & 15;
  const int rbase = wv * 16 + (lane >> 4) * 4;
#pragma unroll
  for (int nt = 0; nt < 3; ++nt) {
    f32x4 a = (nt == 0) ? acc0 : (nt == 1) ? acc1 : acc2;
    int n = n0 + nt * 16 + colc;
    int gsel = n >> 8, jj = n & 255;
    const float* bp = (gsel == 0) ? bu : (gsel == 1) ? br : bn;
    float bias = bp[jj];
#pragma unroll
    for (int rr = 0; rr < 4; ++rr) {
      int m = rbase + rr;  // batch index
      half_t hv = (half_t)(a[rr] + bias);
      if (gsel < 2) {
        ((unsigned short*)hs)[(((size_t)m * TT + t) * HH + jj) * 2 + gsel] =
            __builtin_bit_cast(unsigned short, hv);
      } else {
        nbuf[((size_t)tl * BQ + m) * HH + jj] = hv;
      }
    }
  }
}

// ---------------- Phase B: sequential scan ----------------
// 512 threads (2 waves/SIMD -> 256 VGPR cap). Pair (j = r>>1, p = r&1) owns
// rows {u_j, r_j, n_j}, K-half p: 3*64 packed-f16 h2 regs. One h-read serves
// u AND r. h_j and z_t live in registers; partial sums combined via shfl_xor(1).
// Barriers wait lgkmcnt only -> gate prefetch (depth 2) survives barriers.
// rt uses Wu/xu, zt uses Wr/xr (reference naming quirk); n input is (rt*h)@Wn_h^T.
__global__ __launch_bounds__(512, 2) void gru_rec(
    float* __restrict__ hs,           // u/r gate stash + h output
    const half_t* __restrict__ nbuf,  // n-gate chunk
    const float* __restrict__ h0,
    const float* __restrict__ Wu, const float* __restrict__ Wr,
    const float* __restrict__ Wn,
    float* __restrict__ ht, float* __restrict__ hws,
    int t0, int t1)
{
  __shared__ __align__(16) half_t h2buf[256];
  __shared__ __align__(16) half_t rh2buf[256];

  const int b = blockIdx.x;
  const int r = threadIdx.x;
  const int j = r >> 1;
  const int p = r & 1;

  h2_t wu[64], wr[64], wn[64];
  {
    const float4* pu = (const float4*)(Wu + (size_t)j * (EE + HH) + EE + 128 * p);
    const float4* pr = (const float4*)(Wr + (size_t)j * (EE + HH) + EE + 128 * p);
    const float4* pn = (const float4*)(Wn + (size_t)j * (EE + HH) + EE + 128 * p);
#pragma unroll
    for (int i = 0; i < 32; ++i) {
      float4 a = pu[i];
      h2_t q0, q1;
      q0[0] = (half_t)a.x; q0[1] = (half_t)a.y;
      q1[0] = (half_t)a.z; q1[1] = (half_t)a.w;
      wu[2 * i] = q0; wu[2 * i + 1] = q1;
      float4 c = pr[i];
      q0[0] = (half_t)c.x; q0[1] = (half_t)c.y;
      q1[0] = (half_t)c.z; q1[1] = (half_t)c.w;
      wr[2 * i] = q0; wr[2 * i + 1] = q1;
      float4 d = pn[i];
      q0[0] = (half_t)d.x; q0[1] = (half_t)d.y;
      q1[0] = (half_t)d.z; q1[1] = (half_t)d.w;
      wn[2 * i] = q0; wn[2 * i + 1] = q1;
    }
  }

  float hj = (t0 == 0) ? h0[b * HH + j] : hws[b * HH + j];
  if (p == 0) h2buf[hidx(j)] = (half_t)hj;
  __syncthreads();

  const uint32* urp = (const uint32*)hs + ((size_t)b * TT + t0) * HH + j;
  const half_t* np = nbuf + (size_t)b * HH + j;
  float* hout = hs + ((size_t)b * TT + t0) * HH + j;

  const int nT = t1 - t0;
  uint32 ur0 = urp[0];
  half_t xn0 = np[0];
  const int i1 = (nT > 1) ? 1 : 0;
  uint32 ur1 = urp[(size_t)i1 * HH];
  half_t xn1 = np[(size_t)i1 * BQ * HH];

  const h8_t* hp = (const h8_t*)h2buf + p;
  const h8_t* rp = (const h8_t*)rh2buf + p;

  for (int tl = 0; tl < nT; ++tl) {
    const int t2 = (tl + 2 < nT) ? (tl + 2) : (nT - 1);
    uint32 ur2 = urp[(size_t)t2 * HH];          // in flight ~2 steps
    half_t xn2 = np[(size_t)t2 * BQ * HH];

    // ---- phase 1: u,r matvec over h (this K-half) ----
    float au0 = 0, au1 = 0, au2 = 0, au3 = 0;
    float ar0 = 0, ar1 = 0, ar2 = 0, ar3 = 0;
#pragma unroll
    for (int kk = 0; kk < 16; ++kk) {
      h8_t hv = hp[2 * kk];
      h2_t h01 = __builtin_shufflevector(hv, hv, 0, 1);
      h2_t h23 = __builtin_shufflevector(hv, hv, 2, 3);
      h2_t h45 = __builtin_shufflevector(hv, hv, 4, 5);
      h2_t h67 = __builtin_shufflevector(hv, hv, 6, 7);
      au0 = fdot2_acc(wu[4 * kk + 0], h01, au0);
      au1 = fdot2_acc(wu[4 * kk + 1], h23, au1);
      au2 = fdot2_acc(wu[4 * kk + 2], h45, au2);
      au3 = fdot2_acc(wu[4 * kk + 3], h67, au3);
      ar0 = fdot2_acc(wr[4 * kk + 0], h01, ar0);
      ar1 = fdot2_acc(wr[4 * kk + 1], h23, ar1);
      ar2 = fdot2_acc(wr[4 * kk + 2], h45, ar2);
      ar3 = fdot2_acc(wr[4 * kk + 3], h67, ar3);
    }
    float su = (au0 + au1) + (au2 + au3);
    float sr = (ar0 + ar1) + (ar2 + ar3);
    su += __shfl_xor(su, 1, 64);
    sr += __shfl_xor(sr, 1, 64);
    float xu = (float)__builtin_bit_cast(half_t, (unsigned short)(ur0 & 0xffffu));
    float xr = (float)__builtin_bit_cast(half_t, (unsigned short)(ur0 >> 16));
    float rt = sigmoid_f(xu + su);
    float zt = sigmoid_f(xr + sr);
    if (p == 0) rh2buf[hidx(j)] = (half_t)(rt * hj);
    barrier_lgkm();

    // ---- phase 2: n matvec over rt*h, state update ----
    float an0 = 0, an1 = 0, an2 = 0, an3 = 0;
#pragma unroll
    for (int kk = 0; kk < 16; ++kk) {
      h8_t hv = rp[2 * kk];
      an0 = fdot2_acc(wn[4 * kk + 0], __builtin_shufflevector(hv, hv, 0, 1), an0);
      an1 = fdot2_acc(wn[4 * kk + 1], __builtin_shufflevector(hv, hv, 2, 3), an1);
      an2 = fdot2_acc(wn[4 * kk + 2], __builtin_shufflevector(hv, hv, 4, 5), an2);
      an3 = fdot2_acc(wn[4 * kk + 3], __builtin_shufflevector(hv, hv, 6, 7), an3);
    }
    float sn = (an0 + an1) + (an2 + an3);
    sn += __shfl_xor(sn, 1, 64);
    float pre = (float)xn0 + sn;
    pre = fminf(fmaxf(pre, -15.f), 15.f);
    float e = __expf(-2.f * pre);
    float ntv = (1.f - e) * FRCP(1.f + e);  // tanh
    float hn = (1.f - zt) * ntv + zt * hj;
    hj = hn;
    if (p == 0) {
      h2buf[hidx(j)] = (half_t)hn;
      hout[(size_t)tl * HH] = hn;  // overwrites the consumed u/r gate slot
    }
    barrier_lgkm();

    ur0 = ur1; ur1 = ur2;
    xn0 = xn1; xn1 = xn2;
  }

  if (p == 0) {
    if (t1 == TT) ht[b * HH + j] = hj;
    else hws[b * HH + j] = hj;
  }
}

extern "C" void kernel_launch(void* const* d_in, const int* in_sizes, int n_in,
                              void* d_out, int out_size, void* d_ws, size_t ws_size,
                              hipStream_t stream)
{
  (void)in_sizes; (void)n_in; (void)out_size;
  const float* x  = (const float*)d_in[0];
  const float* h0 = (const float*)d_in[1];
  const float* Wu = (const float*)d_in[2];
  const float* bu = (const float*)d_in[3];
  const float* Wr = (const float*)d_in[4];
  const float* br = (const float*)d_in[5];
  const float* Wn = (const float*)d_in[6];
  const float* bn = (const float*)d_in[7];
  float* hs = (float*)d_out;
  float* ht = hs + (size_t)BQ * TT * HH;
  float* hws = (float*)d_ws;                            // 64 KB h carry
  half_t* nbuf = (half_t*)((char*)d_ws + 65536);        // n-gate chunks

  const size_t per_step = (size_t)BQ * HH * sizeof(half_t);  // 32 KB/step
  size_t avail = (ws_size > 65536) ? ws_size - 65536 : 0;
  int Tc = (int)(avail / per_step);
  if (Tc > TT) Tc = TT;
  if (Tc < 1) Tc = 1;

  for (int t0 = 0; t0 < TT; t0 += Tc) {
    int tc = (TT - t0 < Tc) ? (TT - t0) : Tc;
    gru_xproj<<<dim3(tc, 16), 256, 0, stream>>>(x, Wu, bu, Wr, br, Wn, bn, hs, nbuf, t0);
    gru_rec<<<dim3(BQ), 512, 0, stream>>>(hs, nbuf, h0, Wu, Wr, Wn, ht, hws, t0, t0 + tc);
  }
}

// Round 4
// 2795.955 us; speedup vs baseline: 1.5963x; 1.1555x over previous
//
#include <hip/hip_runtime.h>

typedef _Float16 half_t;
typedef _Float16 h2_t __attribute__((ext_vector_type(2)));
typedef _Float16 h4_t __attribute__((ext_vector_type(4)));
typedef _Float16 h8_t __attribute__((ext_vector_type(8)));
typedef float f32x4 __attribute__((ext_vector_type(4)));
typedef unsigned int uint32;

#define BQ 64
#define TT 2048
#define EE 256
#define HH 256

#if defined(__has_builtin)
#if __has_builtin(__builtin_amdgcn_fdot2)
#define HAVE_FDOT2 1
#endif
#if __has_builtin(__builtin_amdgcn_update_dpp)
#define HAVE_DPP 1
#endif
#if __has_builtin(__builtin_amdgcn_rcpf)
#define FRCP(x) __builtin_amdgcn_rcpf(x)
#endif
#endif
#ifndef FRCP
#define FRCP(x) (1.0f / (x))
#endif

__device__ __forceinline__ float fdot2_acc(h2_t a, h2_t b, float c) {
#ifdef HAVE_FDOT2
  return __builtin_amdgcn_fdot2(a, b, c, false);
#else
  return c + (float)a[0] * (float)b[0] + (float)a[1] * (float)b[1];
#endif
}

__device__ __forceinline__ float dot8(h8_t w, h8_t h, float acc) {
  acc = fdot2_acc(__builtin_shufflevector(w, w, 0, 1), __builtin_shufflevector(h, h, 0, 1), acc);
  acc = fdot2_acc(__builtin_shufflevector(w, w, 2, 3), __builtin_shufflevector(h, h, 2, 3), acc);
  acc = fdot2_acc(__builtin_shufflevector(w, w, 4, 5), __builtin_shufflevector(h, h, 4, 5), acc);
  acc = fdot2_acc(__builtin_shufflevector(w, w, 6, 7), __builtin_shufflevector(h, h, 6, 7), acc);
  return acc;
}

// cross-lane move via DPP quad_perm (VALU pipe, not LDS). 0xB1 = xor1, 0x4E = xor2.
template <int CTRL>
__device__ __forceinline__ float dpp_mov(float v) {
#ifdef HAVE_DPP
  return __builtin_bit_cast(
      float, __builtin_amdgcn_update_dpp(0, __builtin_bit_cast(int, v), CTRL, 0xF, 0xF, true));
#else
  return __shfl_xor(v, (CTRL == 0xB1) ? 1 : 2, 64);
#endif
}

// Reduce 4 per-row partials (v0..v3 = rows 4g..4g+3) over the 8 lanes of a group.
// Returns the FULL sum of row (i&3), present at lanes i and i+4.
__device__ __forceinline__ float reduce8(float v0, float v1, float v2, float v3, int i) {
  const bool b0 = (i & 1) != 0, b1 = (i & 2) != 0;
  float keep0 = b0 ? v1 : v0, send0 = b0 ? v0 : v1;
  float keep1 = b0 ? v3 : v2, send1 = b0 ? v2 : v3;
  float k0 = keep0 + dpp_mov<0xB1>(send0);
  float k1 = keep1 + dpp_mov<0xB1>(send1);
  float keepA = b1 ? k1 : k0, sendA = b1 ? k0 : k1;
  float m = keepA + dpp_mov<0x4E>(sendA);
  return m + __shfl_xor(m, 4, 64);
}

// barrier that drains LDS only: global prefetch stays in flight
__device__ __forceinline__ void barrier_lgkm() {
  asm volatile("s_waitcnt lgkmcnt(0)\n\ts_barrier" ::: "memory");
}

__device__ __forceinline__ float sigmoid_f(float x) {
  x = fminf(fmaxf(x, -30.f), 30.f);
  return FRCP(1.f + __expf(-x));
}

// ---------------- Phase A: input projections ----------------
// One block per timestep t: A (x rows, all 64 batches) staged ONCE, then 16
// N-chunks of 48 gate-rows with double-buffered, padded B tiles (x read 1x).
__device__ __forceinline__ const float4* wsrc(int n, int col, const float* Wu,
                                              const float* Wr, const float* Wn) {
  const int gsel = n >> 8, jj = n & 255;
  const float* W = (gsel == 0) ? Wu : (gsel == 1) ? Wr : Wn;
  return (const float4*)(W + (size_t)jj * (EE + HH) + col);
}

__global__ __launch_bounds__(256) void gru_xproj(
    const float* __restrict__ x,
    const float* __restrict__ Wu, const float* __restrict__ bu,
    const float* __restrict__ Wr, const float* __restrict__ br,
    const float* __restrict__ Wn, const float* __restrict__ bn,
    float* __restrict__ hs, half_t* __restrict__ nbuf, int t0)
{
  __shared__ half_t Asm[64][264];     // +8 pad: 2-way banks only
  __shared__ half_t Bsm[2][48][264];
  const int tid = threadIdx.x;
  const int tl = blockIdx.x;
  const int t = t0 + tl;

  // stage A: flat float4 index q = tid + 256k; row=q>>6 (batch), col=(q&63)*4
#pragma unroll
  for (int k = 0; k < 16; ++k) {
    int q = tid + 256 * k;
    int row = q >> 6, col = (q & 63) * 4;
    float4 v = *(const float4*)(x + ((size_t)row * TT + t) * EE + col);
    h4_t h; h[0] = (half_t)v.x; h[1] = (half_t)v.y; h[2] = (half_t)v.z; h[3] = (half_t)v.w;
    *(h4_t*)(&Asm[row][col]) = h;
  }
  // stage B chunk 0
#pragma unroll
  for (int k = 0; k < 12; ++k) {
    int q = tid + 256 * k;
    int row = q >> 6, col = (q & 63) * 4;
    float4 v = *wsrc(row, col, Wu, Wr, Wn);
    h4_t h; h[0] = (half_t)v.x; h[1] = (half_t)v.y; h[2] = (half_t)v.z; h[3] = (half_t)v.w;
    *(h4_t*)(&Bsm[0][row][col]) = h;
  }
  __syncthreads();

  const int wv = tid >> 6, lane = tid & 63;
  const int rowa = wv * 16 + (lane & 15);
  const int koff = (lane >> 4) * 8;
  h8_t af[8];
#pragma unroll
  for (int ki = 0; ki < 8; ++ki) af[ki] = *(const h8_t*)&Asm[rowa][ki * 32 + koff];

  const int colc = lane & 15;
  const int rbase = wv * 16 + (lane >> 4) * 4;

  for (int c = 0; c < 16; ++c) {
    const int cur = c & 1;
    // prefetch next B chunk into regs
    float4 pf[12];
    if (c < 15) {
#pragma unroll
      for (int k = 0; k < 12; ++k) {
        int q = tid + 256 * k;
        int row = q >> 6, col = (q & 63) * 4;
        pf[k] = *wsrc((c + 1) * 48 + row, col, Wu, Wr, Wn);
      }
    }
    // MFMA on current chunk
    f32x4 acc0 = {0.f, 0.f, 0.f, 0.f}, acc1 = acc0, acc2 = acc0;
#pragma unroll
    for (int ki = 0; ki < 8; ++ki) {
      h8_t b0 = *(const h8_t*)&Bsm[cur][0  + (lane & 15)][ki * 32 + koff];
      h8_t b1 = *(const h8_t*)&Bsm[cur][16 + (lane & 15)][ki * 32 + koff];
      h8_t b2 = *(const h8_t*)&Bsm[cur][32 + (lane & 15)][ki * 32 + koff];
      acc0 = __builtin_amdgcn_mfma_f32_16x16x32_f16(af[ki], b0, acc0, 0, 0, 0);
      acc1 = __builtin_amdgcn_mfma_f32_16x16x32_f16(af[ki], b1, acc1, 0, 0, 0);
      acc2 = __builtin_amdgcn_mfma_f32_16x16x32_f16(af[ki], b2, acc2, 0, 0, 0);
    }
    // write prefetched chunk to the other buffer
    if (c < 15) {
#pragma unroll
      for (int k = 0; k < 12; ++k) {
        int q = tid + 256 * k;
        int row = q >> 6, col = (q & 63) * 4;
        float4 v = pf[k];
        h4_t h; h[0] = (half_t)v.x; h[1] = (half_t)v.y; h[2] = (half_t)v.z; h[3] = (half_t)v.w;
        *(h4_t*)(&Bsm[cur ^ 1][row][col]) = h;
      }
    }
    // epilogue for chunk c (D: col = lane&15, row = (lane>>4)*4 + reg)
#pragma unroll
    for (int nt = 0; nt < 3; ++nt) {
      f32x4 a = (nt == 0) ? acc0 : (nt == 1) ? acc1 : acc2;
      int n = c * 48 + nt * 16 + colc;
      int gsel = n >> 8, jj = n & 255;
      const float* bp = (gsel == 0) ? bu : (gsel == 1) ? br : bn;
      float bias = bp[jj];
#pragma unroll
      for (int rr = 0; rr < 4; ++rr) {
        int m = rbase + rr;  // batch
        half_t hv = (half_t)(a[rr] + bias);
        if (gsel < 2) {
          ((unsigned short*)hs)[(((size_t)m * TT + t) * HH + jj) * 2 + gsel] =
              __builtin_bit_cast(unsigned short, hv);
        } else {
          nbuf[((size_t)tl * BQ + m) * HH + jj] = hv;
        }
      }
    }
    __syncthreads();
  }
}

// ---------------- Phase B: sequential scan ----------------
// 512 threads, group g = tid>>3 (8 lanes) owns rows [4g,4g+4) of u, r, n, h.
// Lane i covers strided K-slice {8*(i+8c)..+8 | c<4}: 4 ds_read_b128/phase.
// Row-reduce over 8 lanes: DPP xor1/xor2 (VALU) + one shfl_xor(4) per gate.
// Lane i owns row 4g+(i&3): h master, rt, zt all stay in registers.
// rt uses Wu/xu, zt uses Wr/xr (reference naming quirk); n input is (rt*h)@Wn_h^T.
__global__ __launch_bounds__(512, 2) void gru_rec(
    float* __restrict__ hs,           // u/r gate stash + h output
    const half_t* __restrict__ nbuf,  // n-gate chunk
    const float* __restrict__ h0,
    const float* __restrict__ Wu, const float* __restrict__ Wr,
    const float* __restrict__ Wn,
    float* __restrict__ ht, float* __restrict__ hws,
    int t0, int t1)
{
  __shared__ __align__(16) half_t h2buf[256];
  __shared__ __align__(16) half_t rh2buf[256];

  const int b = blockIdx.x;
  const int tid = threadIdx.x;
  const int g = tid >> 3;
  const int i = tid & 7;
  const int jmine = 4 * g + (i & 3);

  // weights: w*8[jr][c] = W[4g+jr][EE + 8*(i+8c) .. +8]
  h8_t wu8[4][4], wr8[4][4], wn8[4][4];
#pragma unroll
  for (int jr = 0; jr < 4; ++jr) {
    const float* pu = Wu + (size_t)(4 * g + jr) * (EE + HH) + EE;
    const float* pr = Wr + (size_t)(4 * g + jr) * (EE + HH) + EE;
    const float* pn = Wn + (size_t)(4 * g + jr) * (EE + HH) + EE;
#pragma unroll
    for (int c = 0; c < 4; ++c) {
      int k0 = 8 * (i + 8 * c);
      float4 a0 = *(const float4*)(pu + k0);
      float4 a1 = *(const float4*)(pu + k0 + 4);
      h8_t w;
      w[0] = (half_t)a0.x; w[1] = (half_t)a0.y; w[2] = (half_t)a0.z; w[3] = (half_t)a0.w;
      w[4] = (half_t)a1.x; w[5] = (half_t)a1.y; w[6] = (half_t)a1.z; w[7] = (half_t)a1.w;
      wu8[jr][c] = w;
      a0 = *(const float4*)(pr + k0);
      a1 = *(const float4*)(pr + k0 + 4);
      w[0] = (half_t)a0.x; w[1] = (half_t)a0.y; w[2] = (half_t)a0.z; w[3] = (half_t)a0.w;
      w[4] = (half_t)a1.x; w[5] = (half_t)a1.y; w[6] = (half_t)a1.z; w[7] = (half_t)a1.w;
      wr8[jr][c] = w;
      a0 = *(const float4*)(pn + k0);
      a1 = *(const float4*)(pn + k0 + 4);
      w[0] = (half_t)a0.x; w[1] = (half_t)a0.y; w[2] = (half_t)a0.z; w[3] = (half_t)a0.w;
      w[4] = (half_t)a1.x; w[5] = (half_t)a1.y; w[6] = (half_t)a1.z; w[7] = (half_t)a1.w;
      wn8[jr][c] = w;
    }
  }

  float hm;
  {
    const float* hsrc = (t0 == 0) ? (h0 + (size_t)b * HH) : (hws + (size_t)b * HH);
    hm = hsrc[jmine];
    if (tid < 256) h2buf[tid] = (half_t)hsrc[tid];
  }
  __syncthreads();

  const uint32* urp = (const uint32*)hs + ((size_t)b * TT + t0) * HH + jmine;
  const half_t* np = nbuf + (size_t)b * HH + jmine;
  float* hout = hs + ((size_t)b * TT + t0) * HH + jmine;

  const int nT = t1 - t0;
  uint32 ur0 = urp[0];
  half_t xn0 = np[0];
  const int i1 = (nT > 1) ? 1 : 0;
  uint32 ur1 = urp[(size_t)i1 * HH];
  half_t xn1 = np[(size_t)i1 * BQ * HH];

  for (int tl = 0; tl < nT; ++tl) {
    const int t2 = (tl + 2 < nT) ? (tl + 2) : (nT - 1);
    uint32 ur2 = urp[(size_t)t2 * HH];           // stays in flight across barriers
    half_t xn2 = np[(size_t)t2 * BQ * HH];

    // ---- phase 1: u,r matvecs over h ----
    h8_t hv0 = *(const h8_t*)(h2buf + 8 * i);
    h8_t hv1 = *(const h8_t*)(h2buf + 8 * (i + 8));
    h8_t hv2 = *(const h8_t*)(h2buf + 8 * (i + 16));
    h8_t hv3 = *(const h8_t*)(h2buf + 8 * (i + 24));
    float su[4], sr[4];
#pragma unroll
    for (int jr = 0; jr < 4; ++jr) {
      float a = 0.f, c2 = 0.f;
      a = dot8(wu8[jr][0], hv0, a); a = dot8(wu8[jr][1], hv1, a);
      a = dot8(wu8[jr][2], hv2, a); a = dot8(wu8[jr][3], hv3, a);
      c2 = dot8(wr8[jr][0], hv0, c2); c2 = dot8(wr8[jr][1], hv1, c2);
      c2 = dot8(wr8[jr][2], hv2, c2); c2 = dot8(wr8[jr][3], hv3, c2);
      su[jr] = a; sr[jr] = c2;
    }
    float suf = reduce8(su[0], su[1], su[2], su[3], i);
    float srf = reduce8(sr[0], sr[1], sr[2], sr[3], i);
    float xu = (float)__builtin_bit_cast(half_t, (unsigned short)(ur0 & 0xffffu));
    float xr = (float)__builtin_bit_cast(half_t, (unsigned short)(ur0 >> 16));
    float rt = sigmoid_f(xu + suf);
    float zt = sigmoid_f(xr + srf);
    if (i < 4) rh2buf[jmine] = (half_t)(rt * hm);  // rt * h (pre-matmul!)
    barrier_lgkm();

    // ---- phase 2: n matvec over rt*h, state update ----
    h8_t rv0 = *(const h8_t*)(rh2buf + 8 * i);
    h8_t rv1 = *(const h8_t*)(rh2buf + 8 * (i + 8));
    h8_t rv2 = *(const h8_t*)(rh2buf + 8 * (i + 16));
    h8_t rv3 = *(const h8_t*)(rh2buf + 8 * (i + 24));
    float sn[4];
#pragma unroll
    for (int jr = 0; jr < 4; ++jr) {
      float a = 0.f;
      a = dot8(wn8[jr][0], rv0, a); a = dot8(wn8[jr][1], rv1, a);
      a = dot8(wn8[jr][2], rv2, a); a = dot8(wn8[jr][3], rv3, a);
      sn[jr] = a;
    }
    float snf = reduce8(sn[0], sn[1], sn[2], sn[3], i);
    float pre = (float)xn0 + snf;
    pre = fminf(fmaxf(pre, -15.f), 15.f);
    float e = __expf(-2.f * pre);
    float ntv = (1.f - e) * FRCP(1.f + e);  // tanh
    float hn = (1.f - zt) * ntv + zt * hm;
    hm = hn;
    if (i < 4) {
      h2buf[jmine] = (half_t)hn;
      hout[(size_t)tl * HH] = hn;  // overwrites the consumed u/r gate slot
    }
    barrier_lgkm();

    ur0 = ur1; ur1 = ur2;
    xn0 = xn1; xn1 = xn2;
  }

  if (i < 4) {
    if (t1 == TT) ht[(size_t)b * HH + jmine] = hm;
    else hws[(size_t)b * HH + jmine] = hm;
  }
}

extern "C" void kernel_launch(void* const* d_in, const int* in_sizes, int n_in,
                              void* d_out, int out_size, void* d_ws, size_t ws_size,
                              hipStream_t stream)
{
  (void)in_sizes; (void)n_in; (void)out_size;
  const float* x  = (const float*)d_in[0];
  const float* h0 = (const float*)d_in[1];
  const float* Wu = (const float*)d_in[2];
  const float* bu = (const float*)d_in[3];
  const float* Wr = (const float*)d_in[4];
  const float* br = (const float*)d_in[5];
  const float* Wn = (const float*)d_in[6];
  const float* bn = (const float*)d_in[7];
  float* hs = (float*)d_out;
  float* ht = hs + (size_t)BQ * TT * HH;
  float* hws = (float*)d_ws;                      // 64 KB h carry
  half_t* nbuf = (half_t*)((char*)d_ws + 65536);  // n-gate chunks

  const size_t per_step = (size_t)BQ * HH * sizeof(half_t);  // 32 KB/step
  size_t avail = (ws_size > 65536) ? ws_size - 65536 : 0;
  int Tc = (int)(avail / per_step);
  if (Tc > TT) Tc = TT;
  if (Tc < 1) Tc = 1;

  for (int t0 = 0; t0 < TT; t0 += Tc) {
    int tc = (TT - t0 < Tc) ? (TT - t0) : Tc;
    gru_xproj<<<dim3(tc), 256, 0, stream>>>(x, Wu, bu, Wr, br, Wn, bn, hs, nbuf, t0);
    gru_rec<<<dim3(BQ), 512, 0, stream>>>(hs, nbuf, h0, Wu, Wr, Wn, ht, hws, t0, t0 + tc);
  }
}

// Round 5
// 2753.113 us; speedup vs baseline: 1.6212x; 1.0156x over previous
//
#include <hip/hip_runtime.h>

typedef _Float16 half_t;
typedef _Float16 h2_t __attribute__((ext_vector_type(2)));
typedef _Float16 h4_t __attribute__((ext_vector_type(4)));
typedef _Float16 h8_t __attribute__((ext_vector_type(8)));
typedef float f32x4 __attribute__((ext_vector_type(4)));
typedef unsigned int uint32;

#define BQ 64
#define TT 2048
#define EE 256
#define HH 256

#if defined(__has_builtin)
#if __has_builtin(__builtin_amdgcn_fdot2)
#define HAVE_FDOT2 1
#endif
#if __has_builtin(__builtin_amdgcn_update_dpp)
#define HAVE_DPP 1
#endif
#if __has_builtin(__builtin_amdgcn_rcpf)
#define FRCP(x) __builtin_amdgcn_rcpf(x)
#endif
#endif
#ifndef FRCP
#define FRCP(x) (1.0f / (x))
#endif

__device__ __forceinline__ float fdot2_acc(h2_t a, h2_t b, float c) {
#ifdef HAVE_FDOT2
  return __builtin_amdgcn_fdot2(a, b, c, false);
#else
  return c + (float)a[0] * (float)b[0] + (float)a[1] * (float)b[1];
#endif
}

__device__ __forceinline__ float dot8(h8_t w, h8_t h, float acc) {
  acc = fdot2_acc(__builtin_shufflevector(w, w, 0, 1), __builtin_shufflevector(h, h, 0, 1), acc);
  acc = fdot2_acc(__builtin_shufflevector(w, w, 2, 3), __builtin_shufflevector(h, h, 2, 3), acc);
  acc = fdot2_acc(__builtin_shufflevector(w, w, 4, 5), __builtin_shufflevector(h, h, 4, 5), acc);
  acc = fdot2_acc(__builtin_shufflevector(w, w, 6, 7), __builtin_shufflevector(h, h, 6, 7), acc);
  return acc;
}

// cross-lane move via DPP (VALU pipe, not LDS).
// 0xB1 = quad_perm xor1, 0x4E = quad_perm xor2, 0x141 = row_half_mirror (i <-> 7-i in each 8).
template <int CTRL>
__device__ __forceinline__ float dpp_mov(float v) {
#ifdef HAVE_DPP
  return __builtin_bit_cast(
      float, __builtin_amdgcn_update_dpp(0, __builtin_bit_cast(int, v), CTRL, 0xF, 0xF, true));
#else
  return __shfl_xor(v, (CTRL == 0xB1) ? 1 : (CTRL == 0x4E) ? 2 : 7, 64);
#endif
}

// Reduce 4 per-row partials (v0..v3 = rows 4g..4g+3) over the 8 lanes of a
// group, entirely on the VALU (DPP). Returns the FULL sum of row
// F(i) = (i&3) ^ (3*(i>>2)) — lanes i and 7-i end with the same row.
__device__ __forceinline__ float reduce8(float v0, float v1, float v2, float v3, int i) {
  const bool s0 = (((i & 1) ^ (i >> 2)) & 1) != 0;
  const bool s1 = ((((i >> 1) ^ (i >> 2))) & 1) != 0;
  float keep0 = s0 ? v1 : v0, send0 = s0 ? v0 : v1;
  float keep1 = s0 ? v3 : v2, send1 = s0 ? v2 : v3;
  float k0 = keep0 + dpp_mov<0xB1>(send0);
  float k1 = keep1 + dpp_mov<0xB1>(send1);
  float keepA = s1 ? k1 : k0, sendA = s1 ? k0 : k1;
  float m = keepA + dpp_mov<0x4E>(sendA);
  return m + dpp_mov<0x141>(m);  // mirror: lane i + lane 7-i (same row)
}

// barrier that drains LDS only: global prefetch stays in flight
__device__ __forceinline__ void barrier_lgkm() {
  asm volatile("s_waitcnt lgkmcnt(0)\n\ts_barrier" ::: "memory");
}

__device__ __forceinline__ float sigmoid_f(float x) {
  x = fminf(fmaxf(x, -30.f), 30.f);
  return FRCP(1.f + __expf(-x));
}

// ---------------- Phase A: input projections ----------------
// One block per timestep t: A (x rows, all 64 batches) staged ONCE, then 16
// N-chunks of 48 gate-rows with double-buffered, padded B tiles (x read 1x).
__device__ __forceinline__ const float4* wsrc(int n, int col, const float* Wu,
                                              const float* Wr, const float* Wn) {
  const int gsel = n >> 8, jj = n & 255;
  const float* W = (gsel == 0) ? Wu : (gsel == 1) ? Wr : Wn;
  return (const float4*)(W + (size_t)jj * (EE + HH) + col);
}

__global__ __launch_bounds__(256) void gru_xproj(
    const float* __restrict__ x,
    const float* __restrict__ Wu, const float* __restrict__ bu,
    const float* __restrict__ Wr, const float* __restrict__ br,
    const float* __restrict__ Wn, const float* __restrict__ bn,
    float* __restrict__ hs, half_t* __restrict__ nbuf, int t0)
{
  __shared__ half_t Asm[64][264];     // +8 pad: 2-way banks only
  __shared__ half_t Bsm[2][48][264];
  const int tid = threadIdx.x;
  const int tl = blockIdx.x;
  const int t = t0 + tl;

  // stage A: flat float4 index q = tid + 256k; row=q>>6 (batch), col=(q&63)*4
#pragma unroll
  for (int k = 0; k < 16; ++k) {
    int q = tid + 256 * k;
    int row = q >> 6, col = (q & 63) * 4;
    float4 v = *(const float4*)(x + ((size_t)row * TT + t) * EE + col);
    h4_t h; h[0] = (half_t)v.x; h[1] = (half_t)v.y; h[2] = (half_t)v.z; h[3] = (half_t)v.w;
    *(h4_t*)(&Asm[row][col]) = h;
  }
  // stage B chunk 0
#pragma unroll
  for (int k = 0; k < 12; ++k) {
    int q = tid + 256 * k;
    int row = q >> 6, col = (q & 63) * 4;
    float4 v = *wsrc(row, col, Wu, Wr, Wn);
    h4_t h; h[0] = (half_t)v.x; h[1] = (half_t)v.y; h[2] = (half_t)v.z; h[3] = (half_t)v.w;
    *(h4_t*)(&Bsm[0][row][col]) = h;
  }
  __syncthreads();

  const int wv = tid >> 6, lane = tid & 63;
  const int rowa = wv * 16 + (lane & 15);
  const int koff = (lane >> 4) * 8;
  h8_t af[8];
#pragma unroll
  for (int ki = 0; ki < 8; ++ki) af[ki] = *(const h8_t*)&Asm[rowa][ki * 32 + koff];

  const int colc = lane & 15;
  const int rbase = wv * 16 + (lane >> 4) * 4;

  for (int c = 0; c < 16; ++c) {
    const int cur = c & 1;
    // prefetch next B chunk into regs
    float4 pf[12];
    if (c < 15) {
#pragma unroll
      for (int k = 0; k < 12; ++k) {
        int q = tid + 256 * k;
        int row = q >> 6, col = (q & 63) * 4;
        pf[k] = *wsrc((c + 1) * 48 + row, col, Wu, Wr, Wn);
      }
    }
    // MFMA on current chunk
    f32x4 acc0 = {0.f, 0.f, 0.f, 0.f}, acc1 = acc0, acc2 = acc0;
#pragma unroll
    for (int ki = 0; ki < 8; ++ki) {
      h8_t b0 = *(const h8_t*)&Bsm[cur][0  + (lane & 15)][ki * 32 + koff];
      h8_t b1 = *(const h8_t*)&Bsm[cur][16 + (lane & 15)][ki * 32 + koff];
      h8_t b2 = *(const h8_t*)&Bsm[cur][32 + (lane & 15)][ki * 32 + koff];
      acc0 = __builtin_amdgcn_mfma_f32_16x16x32_f16(af[ki], b0, acc0, 0, 0, 0);
      acc1 = __builtin_amdgcn_mfma_f32_16x16x32_f16(af[ki], b1, acc1, 0, 0, 0);
      acc2 = __builtin_amdgcn_mfma_f32_16x16x32_f16(af[ki], b2, acc2, 0, 0, 0);
    }
    // write prefetched chunk to the other buffer
    if (c < 15) {
#pragma unroll
      for (int k = 0; k < 12; ++k) {
        int q = tid + 256 * k;
        int row = q >> 6, col = (q & 63) * 4;
        float4 v = pf[k];
        h4_t h; h[0] = (half_t)v.x; h[1] = (half_t)v.y; h[2] = (half_t)v.z; h[3] = (half_t)v.w;
        *(h4_t*)(&Bsm[cur ^ 1][row][col]) = h;
      }
    }
    // epilogue for chunk c (D: col = lane&15, row = (lane>>4)*4 + reg)
#pragma unroll
    for (int nt = 0; nt < 3; ++nt) {
      f32x4 a = (nt == 0) ? acc0 : (nt == 1) ? acc1 : acc2;
      int n = c * 48 + nt * 16 + colc;
      int gsel = n >> 8, jj = n & 255;
      const float* bp = (gsel == 0) ? bu : (gsel == 1) ? br : bn;
      float bias = bp[jj];
#pragma unroll
      for (int rr = 0; rr < 4; ++rr) {
        int m = rbase + rr;  // batch
        half_t hv = (half_t)(a[rr] + bias);
        if (gsel < 2) {
          ((unsigned short*)hs)[(((size_t)m * TT + t) * HH + jj) * 2 + gsel] =
              __builtin_bit_cast(unsigned short, hv);
        } else {
          nbuf[((size_t)tl * BQ + m) * HH + jj] = hv;
        }
      }
    }
    __syncthreads();
  }
}

// ---------------- Phase B: sequential scan ----------------
// 512 threads, group g = tid>>3 (8 lanes) owns rows [4g,4g+4) of u, r, n, h.
// Lane i covers strided K-slice {8*(i+8c)..+8 | c<4}: 4 ds_read_b128/phase.
// Row-reduce: all-DPP butterfly (xor1, xor2, half-mirror) — zero LDS traffic.
// Lane i owns row 4g + ((i&3)^(3*(i>>2))): h master, rt, zt stay in registers.
// amdgpu_waves_per_eu(2,2): only 2 waves/SIMD are ever resident (grid=64) --
// raise VGPR budget to 256 so the 192 weight regs stay out of AGPRs.
// rt uses Wu/xu, zt uses Wr/xr (reference naming quirk); n input is (rt*h)@Wn_h^T.
__global__ __launch_bounds__(512)
__attribute__((amdgpu_waves_per_eu(2, 2)))
void gru_rec(
    float* __restrict__ hs,           // u/r gate stash + h output
    const half_t* __restrict__ nbuf,  // n-gate chunk
    const float* __restrict__ h0,
    const float* __restrict__ Wu, const float* __restrict__ Wr,
    const float* __restrict__ Wn,
    float* __restrict__ ht, float* __restrict__ hws,
    int t0, int t1)
{
  __shared__ __align__(16) half_t h2buf[256];
  __shared__ __align__(16) half_t rh2buf[256];

  const int b = blockIdx.x;
  const int tid = threadIdx.x;
  const int g = tid >> 3;
  const int i = tid & 7;
  const int jloc = (i & 3) ^ (3 * (i >> 2));  // row this lane ends up owning
  const int jmine = 4 * g + jloc;

  // weights: w*8[jr][c] = W[4g+jr][EE + 8*(i+8c) .. +8]
  h8_t wu8[4][4], wr8[4][4], wn8[4][4];
#pragma unroll
  for (int jr = 0; jr < 4; ++jr) {
    const float* pu = Wu + (size_t)(4 * g + jr) * (EE + HH) + EE;
    const float* pr = Wr + (size_t)(4 * g + jr) * (EE + HH) + EE;
    const float* pn = Wn + (size_t)(4 * g + jr) * (EE + HH) + EE;
#pragma unroll
    for (int c = 0; c < 4; ++c) {
      int k0 = 8 * (i + 8 * c);
      float4 a0 = *(const float4*)(pu + k0);
      float4 a1 = *(const float4*)(pu + k0 + 4);
      h8_t w;
      w[0] = (half_t)a0.x; w[1] = (half_t)a0.y; w[2] = (half_t)a0.z; w[3] = (half_t)a0.w;
      w[4] = (half_t)a1.x; w[5] = (half_t)a1.y; w[6] = (half_t)a1.z; w[7] = (half_t)a1.w;
      wu8[jr][c] = w;
      a0 = *(const float4*)(pr + k0);
      a1 = *(const float4*)(pr + k0 + 4);
      w[0] = (half_t)a0.x; w[1] = (half_t)a0.y; w[2] = (half_t)a0.z; w[3] = (half_t)a0.w;
      w[4] = (half_t)a1.x; w[5] = (half_t)a1.y; w[6] = (half_t)a1.z; w[7] = (half_t)a1.w;
      wr8[jr][c] = w;
      a0 = *(const float4*)(pn + k0);
      a1 = *(const float4*)(pn + k0 + 4);
      w[0] = (half_t)a0.x; w[1] = (half_t)a0.y; w[2] = (half_t)a0.z; w[3] = (half_t)a0.w;
      w[4] = (half_t)a1.x; w[5] = (half_t)a1.y; w[6] = (half_t)a1.z; w[7] = (half_t)a1.w;
      wn8[jr][c] = w;
    }
  }

  float hm;
  {
    const float* hsrc = (t0 == 0) ? (h0 + (size_t)b * HH) : (hws + (size_t)b * HH);
    hm = hsrc[jmine];
    if (tid < 256) h2buf[tid] = (half_t)hsrc[tid];
  }
  __syncthreads();

  const uint32* urp = (const uint32*)hs + ((size_t)b * TT + t0) * HH + jmine;
  const half_t* np = nbuf + (size_t)b * HH + jmine;
  float* hout = hs + ((size_t)b * TT + t0) * HH + jmine;

  const int nT = t1 - t0;
  uint32 ur0 = urp[0];
  half_t xn0 = np[0];
  const int i1 = (nT > 1) ? 1 : 0;
  uint32 ur1 = urp[(size_t)i1 * HH];
  half_t xn1 = np[(size_t)i1 * BQ * HH];

  for (int tl = 0; tl < nT; ++tl) {
    const int t2 = (tl + 2 < nT) ? (tl + 2) : (nT - 1);
    uint32 ur2 = urp[(size_t)t2 * HH];           // stays in flight across barriers
    half_t xn2 = np[(size_t)t2 * BQ * HH];

    // ---- phase 1: u,r matvecs over h ----
    h8_t hv0 = *(const h8_t*)(h2buf + 8 * i);
    h8_t hv1 = *(const h8_t*)(h2buf + 8 * (i + 8));
    h8_t hv2 = *(const h8_t*)(h2buf + 8 * (i + 16));
    h8_t hv3 = *(const h8_t*)(h2buf + 8 * (i + 24));
    float su[4], sr[4];
#pragma unroll
    for (int jr = 0; jr < 4; ++jr) {
      float a = 0.f, c2 = 0.f;
      a = dot8(wu8[jr][0], hv0, a); a = dot8(wu8[jr][1], hv1, a);
      a = dot8(wu8[jr][2], hv2, a); a = dot8(wu8[jr][3], hv3, a);
      c2 = dot8(wr8[jr][0], hv0, c2); c2 = dot8(wr8[jr][1], hv1, c2);
      c2 = dot8(wr8[jr][2], hv2, c2); c2 = dot8(wr8[jr][3], hv3, c2);
      su[jr] = a; sr[jr] = c2;
    }
    float suf = reduce8(su[0], su[1], su[2], su[3], i);
    float srf = reduce8(sr[0], sr[1], sr[2], sr[3], i);
    float xu = (float)__builtin_bit_cast(half_t, (unsigned short)(ur0 & 0xffffu));
    float xr = (float)__builtin_bit_cast(half_t, (unsigned short)(ur0 >> 16));
    float rt = sigmoid_f(xu + suf);
    float zt = sigmoid_f(xr + srf);
    if (i < 4) rh2buf[jmine] = (half_t)(rt * hm);  // rt * h (pre-matmul!)
    barrier_lgkm();

    // ---- phase 2: n matvec over rt*h, state update ----
    h8_t rv0 = *(const h8_t*)(rh2buf + 8 * i);
    h8_t rv1 = *(const h8_t*)(rh2buf + 8 * (i + 8));
    h8_t rv2 = *(const h8_t*)(rh2buf + 8 * (i + 16));
    h8_t rv3 = *(const h8_t*)(rh2buf + 8 * (i + 24));
    float sn[4];
#pragma unroll
    for (int jr = 0; jr < 4; ++jr) {
      float a = 0.f;
      a = dot8(wn8[jr][0], rv0, a); a = dot8(wn8[jr][1], rv1, a);
      a = dot8(wn8[jr][2], rv2, a); a = dot8(wn8[jr][3], rv3, a);
      sn[jr] = a;
    }
    float snf = reduce8(sn[0], sn[1], sn[2], sn[3], i);
    float pre = (float)xn0 + snf;
    pre = fminf(fmaxf(pre, -15.f), 15.f);
    float e = __expf(-2.f * pre);
    float ntv = (1.f - e) * FRCP(1.f + e);  // tanh
    float hn = (1.f - zt) * ntv + zt * hm;
    hm = hn;
    if (i < 4) {
      h2buf[jmine] = (half_t)hn;
      hout[(size_t)tl * HH] = hn;  // overwrites the consumed u/r gate slot
    }
    barrier_lgkm();

    ur0 = ur1; ur1 = ur2;
    xn0 = xn1; xn1 = xn2;
  }

  if (i < 4) {
    if (t1 == TT) ht[(size_t)b * HH + jmine] = hm;
    else hws[(size_t)b * HH + jmine] = hm;
  }
}

extern "C" void kernel_launch(void* const* d_in, const int* in_sizes, int n_in,
                              void* d_out, int out_size, void* d_ws, size_t ws_size,
                              hipStream_t stream)
{
  (void)in_sizes; (void)n_in; (void)out_size;
  const float* x  = (const float*)d_in[0];
  const float* h0 = (const float*)d_in[1];
  const float* Wu = (const float*)d_in[2];
  const float* bu = (const float*)d_in[3];
  const float* Wr = (const float*)d_in[4];
  const float* br = (const float*)d_in[5];
  const float* Wn = (const float*)d_in[6];
  const float* bn = (const float*)d_in[7];
  float* hs = (float*)d_out;
  float* ht = hs + (size_t)BQ * TT * HH;
  float* hws = (float*)d_ws;                      // 64 KB h carry
  half_t* nbuf = (half_t*)((char*)d_ws + 65536);  // n-gate chunks

  const size_t per_step = (size_t)BQ * HH * sizeof(half_t);  // 32 KB/step
  size_t avail = (ws_size > 65536) ? ws_size - 65536 : 0;
  int Tc = (int)(avail / per_step);
  if (Tc > TT) Tc = TT;
  if (Tc < 1) Tc = 1;

  for (int t0 = 0; t0 < TT; t0 += Tc) {
    int tc = (TT - t0 < Tc) ? (TT - t0) : Tc;
    gru_xproj<<<dim3(tc), 256, 0, stream>>>(x, Wu, bu, Wr, br, Wn, bn, hs, nbuf, t0);
    gru_rec<<<dim3(BQ), 512, 0, stream>>>(hs, nbuf, h0, Wu, Wr, Wn, ht, hws, t0, t0 + tc);
  }
}